// Round 1
// 380.876 us; speedup vs baseline: 1.0035x; 1.0035x over previous
//
#include <hip/hip_runtime.h>
#include <hip/hip_fp16.h>
#include <cstddef>

#define TPB 256
#define BSH 9            // log2(targets per bucket)
#define BTGT 512         // targets per bucket
#define EPA 16           // edges per thread in A0/A
#define ACHUNK (EPA * TPB)

typedef _Float16 f16x8 __attribute__((ext_vector_type(8)));
typedef float    f32x4 __attribute__((ext_vector_type(4)));

// ---------------------------------------------------------------------------
// A0: per-bucket edge counts (LDS-aggregated, padded global atomics).
// ---------------------------------------------------------------------------
__global__ __launch_bounds__(256) void bucket_count_kernel(
        const int* __restrict__ tgt, int* __restrict__ cnt_pad, int E) {
    __shared__ int lcnt[256];
    const int tid = threadIdx.x;
    lcnt[tid] = 0;
    __syncthreads();
    const int base = blockIdx.x * ACHUNK + tid;
#pragma unroll
    for (int j = 0; j < EPA; ++j) {
        int e = base + j * TPB;
        if (e < E) atomicAdd(&lcnt[tgt[e] >> BSH], 1);
    }
    __syncthreads();
    if (lcnt[tid]) atomicAdd(&cnt_pad[tid * 16], lcnt[tid]);
}

// ---------------------------------------------------------------------------
// scanTot: exclusive scan of bucket totals; init padded pass-A cursors.
// ---------------------------------------------------------------------------
__global__ __launch_bounds__(256) void bucket_scan_kernel(
        const int* __restrict__ cnt_pad, int* __restrict__ bucket_start,
        int* __restrict__ cursor_pad, int nb, int E) {
    __shared__ int sm[256];
    const int tid = threadIdx.x;
    int v = (tid < nb) ? cnt_pad[tid * 16] : 0;
    const int orig = v;
    sm[tid] = v;
    __syncthreads();
#pragma unroll
    for (int off = 1; off < 256; off <<= 1) {
        int add = (tid >= off) ? sm[tid - off] : 0;
        __syncthreads();
        sm[tid] += add;
        __syncthreads();
    }
    int excl = sm[tid] - orig;
    if (tid < nb) {
        bucket_start[tid] = excl;
        cursor_pad[tid * 16] = excl;
    }
    if (tid == 0) bucket_start[nb] = E;
}

// ---------------------------------------------------------------------------
// A: bucket scatter. rec (int2) = {(t_local<<23)|(src<<6)|flag, bitcast(w)}.
// ---------------------------------------------------------------------------
__global__ __launch_bounds__(256) void bucket_scatter_kernel(
        const int* __restrict__ tgt, const int* __restrict__ src,
        const float* __restrict__ ew, int* __restrict__ cursor_pad,
        int2* __restrict__ recs, int E) {
    __shared__ int lcnt[256];
    __shared__ int lbase[256];
    const int tid = threadIdx.x;
    lcnt[tid] = 0;
    __syncthreads();
    const int base = blockIdx.x * ACHUNK + tid;
    int px[EPA], pw[EPA], mr[EPA], mb[EPA];
#pragma unroll
    for (int j = 0; j < EPA; ++j) {
        int e = base + j * TPB;
        if (e < E) {
            int t = tgt[e], s = src[e];
            float w = ew[e];
            int flag = (w < 0.0f) ? 1 : 0;
            mb[j] = t >> BSH;
            px[j] = ((t & (BTGT - 1)) << 23) | (s << 6) | flag;
            pw[j] = __float_as_int(w);
            mr[j] = atomicAdd(&lcnt[mb[j]], 1);
        }
    }
    __syncthreads();
    if (lcnt[tid]) lbase[tid] = atomicAdd(&cursor_pad[tid * 16], lcnt[tid]);
    __syncthreads();
#pragma unroll
    for (int j = 0; j < EPA; ++j) {
        int e = base + j * TPB;
        if (e < E) recs[lbase[mb[j]] + mr[j]] = make_int2(px[j], pw[j]);
    }
}

// ---------------------------------------------------------------------------
// B: per-bucket CSR build + fused degrees/dinv/norm-fold.  512 threads (8
// waves) per bucket: halves the strided-pass iteration count vs 256 — this
// kernel is latency-bound at <1 block/CU.
// edat[slot] = {(src<<8)|(flag<<7)|flag, bitcast(w * dinv_sign[t])}.
// Also emits dvv[2*i]=dinvp[i], dvv[2*i+1]=dinvn[i] so gatherX can index
// the src-side scale with a single shift (d.x>>7 == (src<<1)|flag).
// ---------------------------------------------------------------------------
__global__ __launch_bounds__(512) void csr_build_kernel(
        const int* __restrict__ bucket_start, const int2* __restrict__ recs,
        int* __restrict__ rowstart, int2* __restrict__ edat,
        float* __restrict__ dinvp, float* __restrict__ dinvn,
        float* __restrict__ dvv,
        int n, int nb, int E) {
    __shared__ int   hcnt[BTGT];
    __shared__ int   cur[BTGT];
    __shared__ int   sm[BTGT];
    __shared__ float sdp[BTGT];
    __shared__ float sdn[BTGT];
    const int b = blockIdx.x, tid = threadIdx.x;
    const int beg = bucket_start[b], end = bucket_start[b + 1];
    hcnt[tid] = 0;
    sdp[tid] = 0.f;
    sdn[tid] = 0.f;
    __syncthreads();
    for (int i = beg + tid; i < end; i += 512) {
        int2 r = recs[i];
        int tl = ((unsigned)r.x) >> 23;
        atomicAdd(&hcnt[tl], 1);
        float w = __int_as_float(r.y);
        if (w > 0.0f)      atomicAdd(&sdp[tl], w);
        else if (w < 0.0f) atomicAdd(&sdn[tl], -w);
    }
    __syncthreads();
    int own = hcnt[tid];
    sm[tid] = own;
    __syncthreads();
#pragma unroll
    for (int off = 1; off < 512; off <<= 1) {
        int add = (tid >= off) ? sm[tid - off] : 0;
        __syncthreads();
        sm[tid] += add;
        __syncthreads();
    }
    int excl = sm[tid] - own;
    cur[tid] = excl;
    const int t = (b << BSH) + tid;
    if (t < n) {
        rowstart[t] = beg + excl;
        float dp = rsqrtf(sdp[tid] + 1.0f);
        float dn = rsqrtf(sdn[tid] + 1.0f);
        dinvp[t] = dp; dinvn[t] = dn;
        dvv[2 * t] = dp; dvv[2 * t + 1] = dn;
        sdp[tid] = dp; sdn[tid] = dn;
    }
    if (b == nb - 1 && tid == 0) rowstart[n] = E;
    __syncthreads();
    for (int i = beg + tid; i < end; i += 512) {
        int2 r = recs[i];
        int tl = ((unsigned)r.x) >> 23;
        int rank = atomicAdd(&cur[tl], 1);
        float w = __int_as_float(r.y);
        int flag = r.x & 1;
        float nv = w * (flag ? sdn[tl] : sdp[tl]);
        int srcflag = (((r.x >> 6) & 0x1FFFF) << 8) | (flag << 7) | flag;
        edat[beg + rank] = make_int2(srcflag, __float_as_int(nv));
    }
}

// ---------------------------------------------------------------------------
// Convert: x16[row] = fp16(x[row]) (128 B/row, UNSCALED — the per-src dinv
// is applied edge-side from dvv, halving the gather working set 25.6→12.8 MB)
// and the 4 weight matrices to fp16.  No dinv dependency anymore.
// ---------------------------------------------------------------------------
__global__ __launch_bounds__(256) void convert_kernel(
        const float* __restrict__ x,
        const float* __restrict__ W1p, const float* __restrict__ W1n,
        const float* __restrict__ W2p, const float* __restrict__ W2n,
        __half* __restrict__ xs, __half* __restrict__ w16, int n) {
    int idx = blockIdx.x * blockDim.x + threadIdx.x;
    int npx = n * 32;               // feature-pairs of x (flat)
    if (idx < npx) {
        float2 v = *(const float2*)(x + (size_t)idx * 2);
        ((__half2*)xs)[idx] = __floats2half2_rn(v.x, v.y);
    } else {
        int q = idx - npx;
        if (q < 16384) {
            const float* Wsrc = (q < 4096) ? W1p : (q < 8192) ? W1n
                              : (q < 12288) ? W2p : W2n;
            float2 v = *(const float2*)(Wsrc + (q & 4095) * 2);
            ((__half2*)w16)[q] = __floats2half2_rn(v.x, v.y);
        }
    }
}

// ---------------------------------------------------------------------------
// gatherX: layer-1 aggregation in 64-dim x-space.  Per edge: 128-B x16 row
// (12.8 MB working set) + 8-B edat + 4-B dvv scalar (800 KB, L2-resident).
// Row byte offset = (d.x>>1)&~127 (src<<7); dvv index = d.x>>7 = (src<<1)|flag.
// agg[row] = [aggP | aggNs] (fp16, 256 B/row):
//   aggP  = sum_pos nv*dvp[s]*x16[s] + dinvp[t]^2*x16[t]
//   aggNs = sum_neg nv*dvn[s]*x16[s] - dinvn[t]^2*x16[t]   (nv<0 for neg)
// ---------------------------------------------------------------------------
__global__ __launch_bounds__(256) void gatherX_kernel(
        const int* __restrict__ rowstart, const int2* __restrict__ edat,
        const __half* __restrict__ xs, const float* __restrict__ dvv,
        const float* __restrict__ dinvp, const float* __restrict__ dinvn,
        __half* __restrict__ agg, int n) {
    const int lane = threadIdx.x & 63;
    int t = (blockIdx.x * blockDim.x + threadIdx.x) >> 6;
    if (t >= n) return;
    t = __builtin_amdgcn_readfirstlane(t);
    const char* xB = (const char*)xs;
    int beg = rowstart[t], end = rowstart[t + 1];
    float aP0 = 0.f, aP1 = 0.f, aP2 = 0.f, aP3 = 0.f;
    float aN0 = 0.f, aN1 = 0.f, aN2 = 0.f, aN3 = 0.f;
    int e = beg;
    for (; e + 3 < end; e += 4) {
        int2 d0 = edat[e], d1 = edat[e + 1], d2 = edat[e + 2], d3 = edat[e + 3];
        const __half* r0 = (const __half*)(xB + ((((unsigned)d0.x) >> 1) & 0xFFFFFF80u));
        const __half* r1 = (const __half*)(xB + ((((unsigned)d1.x) >> 1) & 0xFFFFFF80u));
        const __half* r2 = (const __half*)(xB + ((((unsigned)d2.x) >> 1) & 0xFFFFFF80u));
        const __half* r3 = (const __half*)(xB + ((((unsigned)d3.x) >> 1) & 0xFFFFFF80u));
        float s0 = dvv[((unsigned)d0.x) >> 7];
        float s1 = dvv[((unsigned)d1.x) >> 7];
        float s2 = dvv[((unsigned)d2.x) >> 7];
        float s3 = dvv[((unsigned)d3.x) >> 7];
        float c0 = __half2float(r0[lane]) * (__int_as_float(d0.y) * s0);
        float c1 = __half2float(r1[lane]) * (__int_as_float(d1.y) * s1);
        float c2 = __half2float(r2[lane]) * (__int_as_float(d2.y) * s2);
        float c3 = __half2float(r3[lane]) * (__int_as_float(d3.y) * s3);
        if (d0.x & 1) aN0 += c0; else aP0 += c0;
        if (d1.x & 1) aN1 += c1; else aP1 += c1;
        if (d2.x & 1) aN2 += c2; else aP2 += c2;
        if (d3.x & 1) aN3 += c3; else aP3 += c3;
    }
    for (; e < end; ++e) {
        int2 d0 = edat[e];
        const __half* r0 = (const __half*)(xB + ((((unsigned)d0.x) >> 1) & 0xFFFFFF80u));
        float s0 = dvv[((unsigned)d0.x) >> 7];
        float c0 = __half2float(r0[lane]) * (__int_as_float(d0.y) * s0);
        if (d0.x & 1) aN0 += c0; else aP0 += c0;
    }
    float dp = dinvp[t], dn = dinvn[t];
    float xv = __half2float(xs[(size_t)t * 64 + lane]);
    float accP = aP0 + aP1 + aP2 + aP3 + dp * dp * xv;
    float accN = aN0 + aN1 + aN2 + aN3 - dn * dn * xv;
    agg[(size_t)t * 128 + lane]      = (__half)accP;
    agg[(size_t)t * 128 + 64 + lane] = (__half)accN;
}

// ---------------------------------------------------------------------------
// Fused MFMA layer-1 GEMM: h = relu([aggP|aggNs] @ [W1p|W1n]^T + (b1p-b1n)).
// Wave = 16 rows x 128 cols, K=128. Layouts m89/m91-verified.
// ---------------------------------------------------------------------------
__global__ __launch_bounds__(256) void gemm1_mfma(
        const __half* __restrict__ agg,
        const __half* __restrict__ w1p, const __half* __restrict__ w1n,
        const float* __restrict__ b1p, const float* __restrict__ b1n,
        __half* __restrict__ h, int n) {
    const int lane = threadIdx.x & 63;
    const int wv = threadIdx.x >> 6;
    const int m = lane & 15, quad = lane >> 4;
    const int row0 = (blockIdx.x * 4 + wv) * 16;
    if (row0 >= n) return;
    int arow = row0 + m; if (arow > n - 1) arow = n - 1;
    f32x4 acc[8];
#pragma unroll
    for (int t = 0; t < 8; ++t) acc[t] = (f32x4){0.f, 0.f, 0.f, 0.f};
#pragma unroll
    for (int kc = 0; kc < 4; ++kc) {
        f16x8 a = *(const f16x8*)(agg + (size_t)arow * 128 + kc * 32 + quad * 8);
        const __half* W = (kc < 2) ? w1p : w1n;
        const int ko = (kc & 1) * 32 + quad * 8;
#pragma unroll
        for (int t = 0; t < 8; ++t) {
            f16x8 bfr = *(const f16x8*)(W + (size_t)(t * 16 + m) * 64 + ko);
            acc[t] = __builtin_amdgcn_mfma_f32_16x16x32_f16(a, bfr, acc[t], 0, 0, 0);
        }
    }
    int rows[4];
#pragma unroll
    for (int r = 0; r < 4; ++r) rows[r] = row0 + quad * 4 + r;
#pragma unroll
    for (int t = 0; t < 8; ++t) {
        int col = t * 16 + m;
        float bd = b1p[col] - b1n[col];
#pragma unroll
        for (int r = 0; r < 4; ++r)
            if (rows[r] < n)
                h[(size_t)rows[r] * 128 + col] = (__half)fmaxf(acc[t][r] + bd, 0.f);
    }
}

// ---------------------------------------------------------------------------
// MFMA GEMM layer 2 (dual): K=128; writes combined g2[row] = [hp2|hn2]
// (256 B rows, matching the gather offset trick). Tiles 0-3 use W2p*dinvp
// (cols 0-63), 4-7 use W2n*dinvn (cols 64-127).
// ---------------------------------------------------------------------------
__global__ __launch_bounds__(256) void gemm2_mfma(
        const __half* __restrict__ h16,
        const __half* __restrict__ wp, const __half* __restrict__ wn,
        const float* __restrict__ dinvp, const float* __restrict__ dinvn,
        __half* __restrict__ g2, int n) {
    const int lane = threadIdx.x & 63;
    const int wv = threadIdx.x >> 6;
    const int m = lane & 15, quad = lane >> 4;
    const int row0 = (blockIdx.x * 4 + wv) * 16;
    if (row0 >= n) return;
    int arow = row0 + m; if (arow > n - 1) arow = n - 1;
    f32x4 acc[8];
#pragma unroll
    for (int t = 0; t < 8; ++t) acc[t] = (f32x4){0.f, 0.f, 0.f, 0.f};
#pragma unroll
    for (int kc = 0; kc < 4; ++kc) {
        f16x8 a = *(const f16x8*)(h16 + (size_t)arow * 128 + kc * 32 + quad * 8);
#pragma unroll
        for (int t = 0; t < 8; ++t) {
            const __half* W = (t < 4) ? wp : wn;
            f16x8 bfr = *(const f16x8*)(W + (size_t)((t & 3) * 16 + m) * 128 + kc * 32 + quad * 8);
            acc[t] = __builtin_amdgcn_mfma_f32_16x16x32_f16(a, bfr, acc[t], 0, 0, 0);
        }
    }
    float sp[4], sn[4]; int rows[4];
#pragma unroll
    for (int r = 0; r < 4; ++r) {
        int rw = row0 + quad * 4 + r;
        rows[r] = rw;
        sp[r] = (rw < n) ? dinvp[rw] : 0.f;
        sn[r] = (rw < n) ? dinvn[rw] : 0.f;
    }
#pragma unroll
    for (int t = 0; t < 8; ++t) {
        int col = (t < 4 ? 0 : 64) + (t & 3) * 16 + m;
#pragma unroll
        for (int r = 0; r < 4; ++r)
            if (rows[r] < n) {
                float s = (t < 4) ? sp[r] : sn[r];
                g2[(size_t)rows[r] * 128 + col] = (__half)(acc[t][r] * s);
            }
    }
}

// ---------------------------------------------------------------------------
// Gather, layer 2 (F=64): reads the selected 128 B half-row of g2 per edge
// (offset = edat.x & ~127), nv signed. fp32 out to d_out.
// ---------------------------------------------------------------------------
__global__ __launch_bounds__(256) void gather64_kernel(
        const int* __restrict__ rowstart, const int2* __restrict__ edat,
        const __half* __restrict__ g2,
        const float* __restrict__ dinvp, const float* __restrict__ dinvn,
        const float* __restrict__ bp, const float* __restrict__ bn,
        float* __restrict__ out, int n) {
    const int lane = threadIdx.x & 63;
    int t = (blockIdx.x * blockDim.x + threadIdx.x) >> 6;
    if (t >= n) return;
    t = __builtin_amdgcn_readfirstlane(t);
    const char* gB = (const char*)g2;
    int beg = rowstart[t], end = rowstart[t + 1];
    float acc0 = 0.f, acc1 = 0.f, acc2 = 0.f, acc3 = 0.f;
    int e = beg;
    for (; e + 3 < end; e += 4) {
        int2 d0 = edat[e], d1 = edat[e + 1], d2 = edat[e + 2], d3 = edat[e + 3];
        const __half* r0 = (const __half*)(gB + (d0.x & 0xFFFFFF80u));
        const __half* r1 = (const __half*)(gB + (d1.x & 0xFFFFFF80u));
        const __half* r2 = (const __half*)(gB + (d2.x & 0xFFFFFF80u));
        const __half* r3 = (const __half*)(gB + (d3.x & 0xFFFFFF80u));
        acc0 += __half2float(r0[lane]) * __int_as_float(d0.y);
        acc1 += __half2float(r1[lane]) * __int_as_float(d1.y);
        acc2 += __half2float(r2[lane]) * __int_as_float(d2.y);
        acc3 += __half2float(r3[lane]) * __int_as_float(d3.y);
    }
    for (; e < end; ++e) {
        int2 d0 = edat[e];
        const __half* r0 = (const __half*)(gB + (d0.x & 0xFFFFFF80u));
        acc0 += __half2float(r0[lane]) * __int_as_float(d0.y);
    }
    const float dp = dinvp[t], dn = dinvn[t];
    float hpv = __half2float(g2[(size_t)t * 128 + lane]);
    float hnv = __half2float(g2[(size_t)t * 128 + 64 + lane]);
    float o = acc0 + acc1 + acc2 + acc3 + hpv * dp + bp[lane] - hnv * dn - bn[lane];
    out[(size_t)t * 64 + lane] = fmaxf(o, 0.f);
}

// ---------------------------------------------------------------------------
extern "C" void kernel_launch(void* const* d_in, const int* in_sizes, int n_in,
                              void* d_out, int out_size, void* d_ws, size_t ws_size,
                              hipStream_t stream) {
    const float* x   = (const float*)d_in[0];
    const int*   ei  = (const int*)d_in[1];
    const float* ew  = (const float*)d_in[2];
    const float* W1p = (const float*)d_in[3];
    const float* b1p = (const float*)d_in[4];
    const float* W1n = (const float*)d_in[5];
    const float* b1n = (const float*)d_in[6];
    const float* W2p = (const float*)d_in[7];
    const float* b2p = (const float*)d_in[8];
    const float* W2n = (const float*)d_in[9];
    const float* b2n = (const float*)d_in[10];

    const int E = in_sizes[2];
    const int n = in_sizes[0] / 64;  // IN = 64
    const int nb = (n + BTGT - 1) >> BSH;
    const int* src = ei;
    const int* tgt = ei + E;

    // ws layout (4B units): cnt_pad[4096] | cursor_pad[4096] | bucket_start[257]
    //   | dinvp[n] | dinvn[n] | dvv[2n] | rowstart[n+1] | (pad16) xs[64n]h |
    //   w16[32768]h | recs[E]int2 | edat[E]int2 | agg[128n]h | h[128n]h.
    //   g2 aliases agg (dead after gemm1).  ~92 MB.
    int* wsi          = (int*)d_ws;
    int* cnt_pad      = wsi;
    int* cursor_pad   = wsi + 4096;
    int* bucket_start = wsi + 8192;
    size_t o = 8452;                                  // 16B-aligned
    float* dinvp    = (float*)(wsi + o);  o += n;
    float* dinvn    = (float*)(wsi + o);  o += n;
    float* dvv      = (float*)(wsi + o);  o += 2 * (size_t)n;
    int*   rowstart = (int*)(wsi + o);    o += n + 1;
    o = (o + 3) & ~(size_t)3;
    __half* xs  = (__half*)(wsi + o);     o += (size_t)n * 32;   // 64 halves/row
    __half* w16 = (__half*)(wsi + o);     o += 16384;
    __half* w1p16 = w16, *w1n16 = w16 + 8192, *w2p16 = w16 + 16384, *w2n16 = w16 + 24576;
    int2* recs = (int2*)(wsi + o);        o += 2 * (size_t)E;
    int2* edat = (int2*)(wsi + o);        o += 2 * (size_t)E;
    __half* agg = (__half*)(wsi + o);     o += (size_t)n * 64;
    __half* h   = (__half*)(wsi + o);
    __half* g2  = agg;
    float*  out = (float*)d_out;

    hipMemsetAsync(cnt_pad, 0, 4096 * sizeof(int), stream);

    const int gridA  = (E + ACHUNK - 1) / ACHUNK;
    const int gridW  = (n * 64 + TPB - 1) / TPB;
    const int gridG  = (n + 63) / 64;     // 64 rows per block (4 waves x 16)
    const int gridCv = (n * 32 + 16384 + TPB - 1) / TPB;

    bucket_count_kernel<<<gridA, TPB, 0, stream>>>(tgt, cnt_pad, E);
    bucket_scan_kernel<<<1, TPB, 0, stream>>>(cnt_pad, bucket_start, cursor_pad, nb, E);
    bucket_scatter_kernel<<<gridA, TPB, 0, stream>>>(tgt, src, ew, cursor_pad, recs, E);
    csr_build_kernel<<<nb, 512, 0, stream>>>(bucket_start, recs, rowstart, edat,
                                             dinvp, dinvn, dvv, n, nb, E);
    convert_kernel<<<gridCv, TPB, 0, stream>>>(x, W1p, W1n, W2p, W2n, xs, w16, n);

    // ---- layer 1: aggregate in x-space, then fused GEMM+bias+relu ----
    gatherX_kernel<<<gridW, TPB, 0, stream>>>(rowstart, edat, xs, dvv, dinvp, dinvn, agg, n);
    gemm1_mfma<<<gridG, TPB, 0, stream>>>(agg, w1p16, w1n16, b1p, b1n, h, n);

    // ---- layer 2: GEMM (combined g2), then gather ----
    gemm2_mfma<<<gridG, TPB, 0, stream>>>(h, w2p16, w2n16, dinvp, dinvn, g2, n);
    gather64_kernel<<<gridW, TPB, 0, stream>>>(rowstart, edat, g2, dinvp, dinvn,
                                               b2p, b2n, out, n);
}

// Round 3
// 360.218 us; speedup vs baseline: 1.0611x; 1.0573x over previous
//
#include <hip/hip_runtime.h>
#include <hip/hip_fp16.h>
#include <cstddef>

#define TPB 256
#define BSH 9            // log2(targets per bucket)
#define BTGT 512         // targets per bucket
#define EPA 16           // edges per thread in A0/A
#define ACHUNK (EPA * TPB)

typedef _Float16 f16x8 __attribute__((ext_vector_type(8)));
typedef float    f32x4 __attribute__((ext_vector_type(4)));

// ---------------------------------------------------------------------------
// A0: per-bucket edge counts (LDS-aggregated, padded global atomics).
// ---------------------------------------------------------------------------
__global__ __launch_bounds__(256) void bucket_count_kernel(
        const int* __restrict__ tgt, int* __restrict__ cnt_pad, int E) {
    __shared__ int lcnt[256];
    const int tid = threadIdx.x;
    lcnt[tid] = 0;
    __syncthreads();
    const int base = blockIdx.x * ACHUNK + tid;
#pragma unroll
    for (int j = 0; j < EPA; ++j) {
        int e = base + j * TPB;
        if (e < E) atomicAdd(&lcnt[tgt[e] >> BSH], 1);
    }
    __syncthreads();
    if (lcnt[tid]) atomicAdd(&cnt_pad[tid * 16], lcnt[tid]);
}

// ---------------------------------------------------------------------------
// scanTot: exclusive scan of bucket totals; init padded pass-A cursors.
// ---------------------------------------------------------------------------
__global__ __launch_bounds__(256) void bucket_scan_kernel(
        const int* __restrict__ cnt_pad, int* __restrict__ bucket_start,
        int* __restrict__ cursor_pad, int nb, int E) {
    __shared__ int sm[256];
    const int tid = threadIdx.x;
    int v = (tid < nb) ? cnt_pad[tid * 16] : 0;
    const int orig = v;
    sm[tid] = v;
    __syncthreads();
#pragma unroll
    for (int off = 1; off < 256; off <<= 1) {
        int add = (tid >= off) ? sm[tid - off] : 0;
        __syncthreads();
        sm[tid] += add;
        __syncthreads();
    }
    int excl = sm[tid] - orig;
    if (tid < nb) {
        bucket_start[tid] = excl;
        cursor_pad[tid * 16] = excl;
    }
    if (tid == 0) bucket_start[nb] = E;
}

// ---------------------------------------------------------------------------
// A: bucket scatter. rec (int2) = {(t_local<<23)|(src<<6)|flag, bitcast(w)}.
// ---------------------------------------------------------------------------
__global__ __launch_bounds__(256) void bucket_scatter_kernel(
        const int* __restrict__ tgt, const int* __restrict__ src,
        const float* __restrict__ ew, int* __restrict__ cursor_pad,
        int2* __restrict__ recs, int E) {
    __shared__ int lcnt[256];
    __shared__ int lbase[256];
    const int tid = threadIdx.x;
    lcnt[tid] = 0;
    __syncthreads();
    const int base = blockIdx.x * ACHUNK + tid;
    int px[EPA], pw[EPA], mr[EPA], mb[EPA];
#pragma unroll
    for (int j = 0; j < EPA; ++j) {
        int e = base + j * TPB;
        if (e < E) {
            int t = tgt[e], s = src[e];
            float w = ew[e];
            int flag = (w < 0.0f) ? 1 : 0;
            mb[j] = t >> BSH;
            px[j] = ((t & (BTGT - 1)) << 23) | (s << 6) | flag;
            pw[j] = __float_as_int(w);
            mr[j] = atomicAdd(&lcnt[mb[j]], 1);
        }
    }
    __syncthreads();
    if (lcnt[tid]) lbase[tid] = atomicAdd(&cursor_pad[tid * 16], lcnt[tid]);
    __syncthreads();
#pragma unroll
    for (int j = 0; j < EPA; ++j) {
        int e = base + j * TPB;
        if (e < E) recs[lbase[mb[j]] + mr[j]] = make_int2(px[j], pw[j]);
    }
}

// ---------------------------------------------------------------------------
// B1: per-bucket degrees + dinv + rowstart (scan).  512 threads (8 waves).
// Emits dvv[2*i]=dinvp[i], dvv[2*i+1]=dinvn[i] (800 KB, L2-resident) so the
// NEXT kernel can fold the FULL edge norm into edat.
// ---------------------------------------------------------------------------
__global__ __launch_bounds__(512) void csr_deg_kernel(
        const int* __restrict__ bucket_start, const int2* __restrict__ recs,
        int* __restrict__ rowstart,
        float* __restrict__ dinvp, float* __restrict__ dinvn,
        float* __restrict__ dvv,
        int n, int nb, int E) {
    __shared__ int   hcnt[BTGT];
    __shared__ int   sm[BTGT];
    __shared__ float sdp[BTGT];
    __shared__ float sdn[BTGT];
    const int b = blockIdx.x, tid = threadIdx.x;
    const int beg = bucket_start[b], end = bucket_start[b + 1];
    hcnt[tid] = 0;
    sdp[tid] = 0.f;
    sdn[tid] = 0.f;
    __syncthreads();
    for (int i = beg + tid; i < end; i += 512) {
        int2 r = recs[i];
        int tl = ((unsigned)r.x) >> 23;
        atomicAdd(&hcnt[tl], 1);
        float w = __int_as_float(r.y);
        if (w > 0.0f)      atomicAdd(&sdp[tl], w);
        else if (w < 0.0f) atomicAdd(&sdn[tl], -w);
    }
    __syncthreads();
    int own = hcnt[tid];
    sm[tid] = own;
    __syncthreads();
#pragma unroll
    for (int off = 1; off < 512; off <<= 1) {
        int add = (tid >= off) ? sm[tid - off] : 0;
        __syncthreads();
        sm[tid] += add;
        __syncthreads();
    }
    int excl = sm[tid] - own;
    const int t = (b << BSH) + tid;
    if (t < n) {
        rowstart[t] = beg + excl;
        float dp = rsqrtf(sdp[tid] + 1.0f);
        float dn = rsqrtf(sdn[tid] + 1.0f);
        dinvp[t] = dp; dinvn[t] = dn;
        dvv[2 * t] = dp; dvv[2 * t + 1] = dn;
    }
    if (b == nb - 1 && tid == 0) rowstart[n] = E;
}

// ---------------------------------------------------------------------------
// B2: per-bucket edat fill.  Runs after csr_deg (kernel boundary = global
// barrier), so dvv is complete for ALL nodes.  Folds the FULL norm
// nv = dinv_sel[src] * w * dinv_sel[tgt] into edat.y — the gathers then do
// zero extra loads per edge and BOTH downstream row buffers (xs, g2) are
// stored RAW (no dinv pre-scale anywhere else).
// edat[slot] = {(src<<8)|(flag<<7)|flag, bitcast(nv)}.
// ---------------------------------------------------------------------------
__global__ __launch_bounds__(512) void csr_edat_kernel(
        const int* __restrict__ bucket_start, const int2* __restrict__ recs,
        const int* __restrict__ rowstart, const float* __restrict__ dvv,
        int2* __restrict__ edat, int n) {
    __shared__ int cur[BTGT];
    const int b = blockIdx.x, tid = threadIdx.x;
    const int beg = bucket_start[b], end = bucket_start[b + 1];
    const int t0 = b << BSH;
    const int t = t0 + tid;
    cur[tid] = (t < n) ? rowstart[t] : 0;   // absolute slot cursors
    __syncthreads();
    for (int i = beg + tid; i < end; i += 512) {
        int2 r = recs[i];
        int tl = ((unsigned)r.x) >> 23;
        int rank = atomicAdd(&cur[tl], 1);
        float w = __int_as_float(r.y);
        int flag = r.x & 1;
        int s = (r.x >> 6) & 0x1FFFF;
        float nv = w * dvv[2 * s + flag] * dvv[2 * (t0 + tl) + flag];
        int srcflag = (s << 8) | (flag << 7) | flag;
        edat[rank] = make_int2(srcflag, __float_as_int(nv));
    }
}

// ---------------------------------------------------------------------------
// Convert: x16[row] = fp16(x[row]) (128 B/row, unscaled) and the 4 weight
// matrices to fp16.
// ---------------------------------------------------------------------------
__global__ __launch_bounds__(256) void convert_kernel(
        const float* __restrict__ x,
        const float* __restrict__ W1p, const float* __restrict__ W1n,
        const float* __restrict__ W2p, const float* __restrict__ W2n,
        __half* __restrict__ xs, __half* __restrict__ w16, int n) {
    int idx = blockIdx.x * blockDim.x + threadIdx.x;
    int npx = n * 32;               // feature-pairs of x (flat)
    if (idx < npx) {
        float2 v = *(const float2*)(x + (size_t)idx * 2);
        ((__half2*)xs)[idx] = __floats2half2_rn(v.x, v.y);
    } else {
        int q = idx - npx;
        if (q < 16384) {
            const float* Wsrc = (q < 4096) ? W1p : (q < 8192) ? W1n
                              : (q < 12288) ? W2p : W2n;
            float2 v = *(const float2*)(Wsrc + (q & 4095) * 2);
            ((__half2*)w16)[q] = __floats2half2_rn(v.x, v.y);
        }
    }
}

// ---------------------------------------------------------------------------
// gatherX: layer-1 aggregation in 64-dim x-space.  Per edge: one 128-B x16
// row read + 8-B edat (nt, streamed).  Full norm pre-folded in edat.y —
// chain is edat -> row -> FMA, with 8 independent rows in flight.
// agg[row] = [aggP | aggNs] (fp16, 256 B/row, nt store):
//   aggP  = sum_pos nv*x16[src] + dinvp[t]^2*x16[t]
//   aggNs = sum_neg nv*x16[src] - dinvn[t]^2*x16[t]   (nv<0 for neg edges)
// ---------------------------------------------------------------------------
__global__ __launch_bounds__(256) void gatherX_kernel(
        const int* __restrict__ rowstart, const int2* __restrict__ edat,
        const __half* __restrict__ xs,
        const float* __restrict__ dinvp, const float* __restrict__ dinvn,
        __half* __restrict__ agg, int n) {
    const int lane = threadIdx.x & 63;
    int t = (blockIdx.x * blockDim.x + threadIdx.x) >> 6;
    if (t >= n) return;
    t = __builtin_amdgcn_readfirstlane(t);
    const char* xB = (const char*)xs;
    int beg = rowstart[t], end = rowstart[t + 1];
    float aP[8], aN[8];
#pragma unroll
    for (int j = 0; j < 8; ++j) { aP[j] = 0.f; aN[j] = 0.f; }
    int e = beg;
    for (; e + 7 < end; e += 8) {
        unsigned long long dv[8];
#pragma unroll
        for (int j = 0; j < 8; ++j)
            dv[j] = __builtin_nontemporal_load(
                        (const unsigned long long*)(edat + e + j));
        const __half* r[8];
        float nvv[8];
        int fl[8];
#pragma unroll
        for (int j = 0; j < 8; ++j) {
            unsigned dx = (unsigned)dv[j];
            r[j]   = (const __half*)(xB + ((dx >> 1) & 0xFFFFFF80u));
            nvv[j] = __int_as_float((int)(dv[j] >> 32));
            fl[j]  = dx & 1;
        }
#pragma unroll
        for (int j = 0; j < 8; ++j) {
            float c = __half2float(r[j][lane]) * nvv[j];
            if (fl[j]) aN[j] += c; else aP[j] += c;
        }
    }
    for (; e + 3 < end; e += 4) {
        unsigned long long dv[4];
#pragma unroll
        for (int j = 0; j < 4; ++j)
            dv[j] = __builtin_nontemporal_load(
                        (const unsigned long long*)(edat + e + j));
#pragma unroll
        for (int j = 0; j < 4; ++j) {
            unsigned dx = (unsigned)dv[j];
            const __half* r = (const __half*)(xB + ((dx >> 1) & 0xFFFFFF80u));
            float c = __half2float(r[lane]) * __int_as_float((int)(dv[j] >> 32));
            if (dx & 1) aN[j] += c; else aP[j] += c;
        }
    }
    for (; e < end; ++e) {
        unsigned long long dv = __builtin_nontemporal_load(
                                    (const unsigned long long*)(edat + e));
        unsigned dx = (unsigned)dv;
        const __half* r = (const __half*)(xB + ((dx >> 1) & 0xFFFFFF80u));
        float c = __half2float(r[lane]) * __int_as_float((int)(dv >> 32));
        if (dx & 1) aN[0] += c; else aP[0] += c;
    }
    float accP = ((aP[0] + aP[1]) + (aP[2] + aP[3]))
               + ((aP[4] + aP[5]) + (aP[6] + aP[7]));
    float accN = ((aN[0] + aN[1]) + (aN[2] + aN[3]))
               + ((aN[4] + aN[5]) + (aN[6] + aN[7]));
    float dp = dinvp[t], dn = dinvn[t];
    float xv = __half2float(xs[(size_t)t * 64 + lane]);
    accP += dp * dp * xv;
    accN -= dn * dn * xv;
    __builtin_nontemporal_store(__half_as_ushort((__half)accP),
        (unsigned short*)(agg + (size_t)t * 128 + lane));
    __builtin_nontemporal_store(__half_as_ushort((__half)accN),
        (unsigned short*)(agg + (size_t)t * 128 + 64 + lane));
}

// ---------------------------------------------------------------------------
// Fused MFMA layer-1 GEMM: h = relu([aggP|aggNs] @ [W1p|W1n]^T + (b1p-b1n)).
// Wave = 16 rows x 128 cols, K=128. Layouts m89/m91-verified.
// ---------------------------------------------------------------------------
__global__ __launch_bounds__(256) void gemm1_mfma(
        const __half* __restrict__ agg,
        const __half* __restrict__ w1p, const __half* __restrict__ w1n,
        const float* __restrict__ b1p, const float* __restrict__ b1n,
        __half* __restrict__ h, int n) {
    const int lane = threadIdx.x & 63;
    const int wv = threadIdx.x >> 6;
    const int m = lane & 15, quad = lane >> 4;
    const int row0 = (blockIdx.x * 4 + wv) * 16;
    if (row0 >= n) return;
    int arow = row0 + m; if (arow > n - 1) arow = n - 1;
    f32x4 acc[8];
#pragma unroll
    for (int t = 0; t < 8; ++t) acc[t] = (f32x4){0.f, 0.f, 0.f, 0.f};
#pragma unroll
    for (int kc = 0; kc < 4; ++kc) {
        f16x8 a = *(const f16x8*)(agg + (size_t)arow * 128 + kc * 32 + quad * 8);
        const __half* W = (kc < 2) ? w1p : w1n;
        const int ko = (kc & 1) * 32 + quad * 8;
#pragma unroll
        for (int t = 0; t < 8; ++t) {
            f16x8 bfr = *(const f16x8*)(W + (size_t)(t * 16 + m) * 64 + ko);
            acc[t] = __builtin_amdgcn_mfma_f32_16x16x32_f16(a, bfr, acc[t], 0, 0, 0);
        }
    }
    int rows[4];
#pragma unroll
    for (int r = 0; r < 4; ++r) rows[r] = row0 + quad * 4 + r;
#pragma unroll
    for (int t = 0; t < 8; ++t) {
        int col = t * 16 + m;
        float bd = b1p[col] - b1n[col];
#pragma unroll
        for (int r = 0; r < 4; ++r)
            if (rows[r] < n)
                h[(size_t)rows[r] * 128 + col] = (__half)fmaxf(acc[t][r] + bd, 0.f);
    }
}

// ---------------------------------------------------------------------------
// MFMA GEMM layer 2 (dual): K=128; writes combined g2[row] = [hp2|hn2]
// RAW (no dinv scale — the full norm now lives in edat.y; the self-loop
// terms in gather64 use dinv^2 explicitly).
// ---------------------------------------------------------------------------
__global__ __launch_bounds__(256) void gemm2_mfma(
        const __half* __restrict__ h16,
        const __half* __restrict__ wp, const __half* __restrict__ wn,
        __half* __restrict__ g2, int n) {
    const int lane = threadIdx.x & 63;
    const int wv = threadIdx.x >> 6;
    const int m = lane & 15, quad = lane >> 4;
    const int row0 = (blockIdx.x * 4 + wv) * 16;
    if (row0 >= n) return;
    int arow = row0 + m; if (arow > n - 1) arow = n - 1;
    f32x4 acc[8];
#pragma unroll
    for (int t = 0; t < 8; ++t) acc[t] = (f32x4){0.f, 0.f, 0.f, 0.f};
#pragma unroll
    for (int kc = 0; kc < 4; ++kc) {
        f16x8 a = *(const f16x8*)(h16 + (size_t)arow * 128 + kc * 32 + quad * 8);
#pragma unroll
        for (int t = 0; t < 8; ++t) {
            const __half* W = (t < 4) ? wp : wn;
            f16x8 bfr = *(const f16x8*)(W + (size_t)((t & 3) * 16 + m) * 128 + kc * 32 + quad * 8);
            acc[t] = __builtin_amdgcn_mfma_f32_16x16x32_f16(a, bfr, acc[t], 0, 0, 0);
        }
    }
    int rows[4];
#pragma unroll
    for (int r = 0; r < 4; ++r) rows[r] = row0 + quad * 4 + r;
#pragma unroll
    for (int t = 0; t < 8; ++t) {
        int col = (t < 4 ? 0 : 64) + (t & 3) * 16 + m;
#pragma unroll
        for (int r = 0; r < 4; ++r)
            if (rows[r] < n)
                g2[(size_t)rows[r] * 128 + col] = (__half)acc[t][r];
    }
}

// ---------------------------------------------------------------------------
// Gather, layer 2 (F=64): reads the selected 128 B half-row of g2 per edge
// (offset = edat.x & ~127), nv = full norm (signed), unroll 8.
// Self-loop terms: +hp2[t]*dp^2  -hn2[t]*dn^2.  fp32 out to d_out.
// ---------------------------------------------------------------------------
__global__ __launch_bounds__(256) void gather64_kernel(
        const int* __restrict__ rowstart, const int2* __restrict__ edat,
        const __half* __restrict__ g2,
        const float* __restrict__ dinvp, const float* __restrict__ dinvn,
        const float* __restrict__ bp, const float* __restrict__ bn,
        float* __restrict__ out, int n) {
    const int lane = threadIdx.x & 63;
    int t = (blockIdx.x * blockDim.x + threadIdx.x) >> 6;
    if (t >= n) return;
    t = __builtin_amdgcn_readfirstlane(t);
    const char* gB = (const char*)g2;
    int beg = rowstart[t], end = rowstart[t + 1];
    float ac[8];
#pragma unroll
    for (int j = 0; j < 8; ++j) ac[j] = 0.f;
    int e = beg;
    for (; e + 7 < end; e += 8) {
        unsigned long long dv[8];
#pragma unroll
        for (int j = 0; j < 8; ++j)
            dv[j] = __builtin_nontemporal_load(
                        (const unsigned long long*)(edat + e + j));
#pragma unroll
        for (int j = 0; j < 8; ++j) {
            unsigned dx = (unsigned)dv[j];
            const __half* r = (const __half*)(gB + (dx & 0xFFFFFF80u));
            ac[j] += __half2float(r[lane]) * __int_as_float((int)(dv[j] >> 32));
        }
    }
    for (; e + 3 < end; e += 4) {
        unsigned long long dv[4];
#pragma unroll
        for (int j = 0; j < 4; ++j)
            dv[j] = __builtin_nontemporal_load(
                        (const unsigned long long*)(edat + e + j));
#pragma unroll
        for (int j = 0; j < 4; ++j) {
            unsigned dx = (unsigned)dv[j];
            const __half* r = (const __half*)(gB + (dx & 0xFFFFFF80u));
            ac[j] += __half2float(r[lane]) * __int_as_float((int)(dv[j] >> 32));
        }
    }
    for (; e < end; ++e) {
        unsigned long long dv = __builtin_nontemporal_load(
                                    (const unsigned long long*)(edat + e));
        unsigned dx = (unsigned)dv;
        const __half* r = (const __half*)(gB + (dx & 0xFFFFFF80u));
        ac[0] += __half2float(r[lane]) * __int_as_float((int)(dv >> 32));
    }
    float acc = ((ac[0] + ac[1]) + (ac[2] + ac[3]))
              + ((ac[4] + ac[5]) + (ac[6] + ac[7]));
    const float dp = dinvp[t], dn = dinvn[t];
    float hpv = __half2float(g2[(size_t)t * 128 + lane]);
    float hnv = __half2float(g2[(size_t)t * 128 + 64 + lane]);
    float o = acc + hpv * dp * dp + bp[lane] - hnv * dn * dn - bn[lane];
    __builtin_nontemporal_store(fmaxf(o, 0.f), out + (size_t)t * 64 + lane);
}

// ---------------------------------------------------------------------------
extern "C" void kernel_launch(void* const* d_in, const int* in_sizes, int n_in,
                              void* d_out, int out_size, void* d_ws, size_t ws_size,
                              hipStream_t stream) {
    const float* x   = (const float*)d_in[0];
    const int*   ei  = (const int*)d_in[1];
    const float* ew  = (const float*)d_in[2];
    const float* W1p = (const float*)d_in[3];
    const float* b1p = (const float*)d_in[4];
    const float* W1n = (const float*)d_in[5];
    const float* b1n = (const float*)d_in[6];
    const float* W2p = (const float*)d_in[7];
    const float* b2p = (const float*)d_in[8];
    const float* W2n = (const float*)d_in[9];
    const float* b2n = (const float*)d_in[10];

    const int E = in_sizes[2];
    const int n = in_sizes[0] / 64;  // IN = 64
    const int nb = (n + BTGT - 1) >> BSH;
    const int* src = ei;
    const int* tgt = ei + E;

    // ws layout (4B units): cnt_pad[4096] | cursor_pad[4096] | bucket_start[257]
    //   | dinvp[n] | dinvn[n] | dvv[2n] | rowstart[n+1] | (pad16) xs[64n]h |
    //   w16[32768]h | recs[E]int2 | edat[E]int2 | agg[128n]h | h[128n]h.
    //   g2 aliases agg (dead after gemm1).  ~92 MB.
    int* wsi          = (int*)d_ws;
    int* cnt_pad      = wsi;
    int* cursor_pad   = wsi + 4096;
    int* bucket_start = wsi + 8192;
    size_t o = 8452;                                  // 16B-aligned
    float* dinvp    = (float*)(wsi + o);  o += n;
    float* dinvn    = (float*)(wsi + o);  o += n;
    float* dvv      = (float*)(wsi + o);  o += 2 * (size_t)n;
    int*   rowstart = (int*)(wsi + o);    o += n + 1;
    o = (o + 3) & ~(size_t)3;
    __half* xs  = (__half*)(wsi + o);     o += (size_t)n * 32;   // 64 halves/row
    __half* w16 = (__half*)(wsi + o);     o += 16384;
    __half* w1p16 = w16, *w1n16 = w16 + 8192, *w2p16 = w16 + 16384, *w2n16 = w16 + 24576;
    int2* recs = (int2*)(wsi + o);        o += 2 * (size_t)E;
    int2* edat = (int2*)(wsi + o);        o += 2 * (size_t)E;
    __half* agg = (__half*)(wsi + o);     o += (size_t)n * 64;
    __half* h   = (__half*)(wsi + o);
    __half* g2  = agg;
    float*  out = (float*)d_out;

    hipMemsetAsync(cnt_pad, 0, 4096 * sizeof(int), stream);

    const int gridA  = (E + ACHUNK - 1) / ACHUNK;
    const int gridW  = (n * 64 + TPB - 1) / TPB;
    const int gridG  = (n + 63) / 64;     // 64 rows per block (4 waves x 16)
    const int gridCv = (n * 32 + 16384 + TPB - 1) / TPB;

    bucket_count_kernel<<<gridA, TPB, 0, stream>>>(tgt, cnt_pad, E);
    bucket_scan_kernel<<<1, TPB, 0, stream>>>(cnt_pad, bucket_start, cursor_pad, nb, E);
    bucket_scatter_kernel<<<gridA, TPB, 0, stream>>>(tgt, src, ew, cursor_pad, recs, E);
    csr_deg_kernel<<<nb, 512, 0, stream>>>(bucket_start, recs, rowstart,
                                           dinvp, dinvn, dvv, n, nb, E);
    csr_edat_kernel<<<nb, 512, 0, stream>>>(bucket_start, recs, rowstart, dvv,
                                            edat, n);
    convert_kernel<<<gridCv, TPB, 0, stream>>>(x, W1p, W1n, W2p, W2n, xs, w16, n);

    // ---- layer 1: aggregate in x-space, then fused GEMM+bias+relu ----
    gatherX_kernel<<<gridW, TPB, 0, stream>>>(rowstart, edat, xs, dinvp, dinvn, agg, n);
    gemm1_mfma<<<gridG, TPB, 0, stream>>>(agg, w1p16, w1n16, b1p, b1n, h, n);

    // ---- layer 2: GEMM (combined g2), then gather ----
    gemm2_mfma<<<gridG, TPB, 0, stream>>>(h, w2p16, w2n16, g2, n);
    gather64_kernel<<<gridW, TPB, 0, stream>>>(rowstart, edat, g2, dinvp, dinvn,
                                               b2p, b2n, out, n);
}